// Round 9
// baseline (340.882 us; speedup 1.0000x reference)
//
#include <hip/hip_runtime.h>
#include <hip/hip_bf16.h>
#include <stdint.h>

typedef __bf16 bh;
typedef __bf16 bf16x8 __attribute__((ext_vector_type(8)));
typedef float f32x4 __attribute__((ext_vector_type(4)));
typedef unsigned int u32;

#define B_  32
#define S_  512
#define R_  196
#define H_  1024
#define BH  (B_ * H_)

// ---------------------------------------------------------------- helpers

__device__ __forceinline__ float fast_tanh(float x) {
  x = fminf(10.f, fmaxf(-10.f, x));
  float e = __expf(2.f * x);
  return (e - 1.f) / (e + 1.f);
}

__device__ __forceinline__ bf16x8 cvt8(const float4 a, const float4 b) {
  bf16x8 r;
  r[0] = (bh)a.x; r[1] = (bh)a.y; r[2] = (bh)a.z; r[3] = (bh)a.w;
  r[4] = (bh)b.x; r[5] = (bh)b.y; r[6] = (bh)b.z; r[7] = (bh)b.w;
  return r;
}

// ---------------------------------------------------------------- kernel 1
// Fused GEMM + tanh + weighted-reduce, no global atomics. FP32 inputs,
// converted to bf16 during LDS staging. 128x128 tile, BK=32, 4 waves of
// 64x64, 16x16x32 bf16 MFMA.
//   sPart[m*8 + ny] = sum_{o in n-block ny} w[o] * tanh( sum_h X[m,h]*W[o,h] )
// dns job: X=dns (M=16384), W=W_d2, w=wD -> sPartD
// img job: X=img (M=6272),  W=W_i1, w=wB -> sPartB
// (The W_d1/wA/b terms of the reference cancel under softmax shift-invariance.)

__global__ __launch_bounds__(256, 2)
void score_gemm_kernel(const float* __restrict__ dns, const float* __restrict__ img,
                       const float* __restrict__ Wd2, const float* __restrict__ Wi1,
                       const float* __restrict__ watt1, const float* __restrict__ watt2,
                       float* __restrict__ sPartD, float* __restrict__ sPartB) {
  __shared__ __align__(16) bh As[128 * 32];
  __shared__ __align__(16) bh Bs[128 * 32];
  __shared__ float sred[128];

  const int tid = threadIdx.x;
  const int wave = tid >> 6, lane = tid & 63;
  const int bx = blockIdx.x, ny = blockIdx.y;

  const float* X; const float* W; const float* w; float* sp; int m0;
  if (bx < 128) { X = dns; W = Wd2; w = watt2 + H_; sp = sPartD; m0 = bx * 128; }
  else          { X = img; W = Wi1; w = watt1 + H_; sp = sPartB; m0 = (bx - 128) * 128; }
  const int n0 = ny * 128;

  // staging: thread t covers rows r0=t>>2 and r0+64, 8 elems at seg
  const int r0  = tid >> 2;
  const int r1  = r0 + 64;
  const int seg = (tid & 3) * 8;

  const float* Ag0 = X + ((size_t)(m0 + r0) * H_ + seg);
  const float* Ag1 = X + ((size_t)(m0 + r1) * H_ + seg);
  const float* Bg0 = W + ((size_t)(n0 + r0) * H_ + seg);
  const float* Bg1 = W + ((size_t)(n0 + r1) * H_ + seg);

  bh* Al0 = As + r0 * 32 + seg;
  bh* Al1 = As + r1 * 32 + seg;
  bh* Bl0 = Bs + r0 * 32 + seg;
  bh* Bl1 = Bs + r1 * 32 + seg;

  const int wm = wave >> 1, wn = wave & 1;
  const int col = lane & 15, quad = lane >> 4;

  f32x4 acc[4][4] = {};

  float4 qa00 = *(const float4*)(Ag0),     qa01 = *(const float4*)(Ag0 + 4);
  float4 qa10 = *(const float4*)(Ag1),     qa11 = *(const float4*)(Ag1 + 4);
  float4 qb00 = *(const float4*)(Bg0),     qb01 = *(const float4*)(Bg0 + 4);
  float4 qb10 = *(const float4*)(Bg1),     qb11 = *(const float4*)(Bg1 + 4);

  for (int kt = 0; kt < 32; ++kt) {
    if (kt) __syncthreads();
    *(bf16x8*)Al0 = cvt8(qa00, qa01);
    *(bf16x8*)Al1 = cvt8(qa10, qa11);
    *(bf16x8*)Bl0 = cvt8(qb00, qb01);
    *(bf16x8*)Bl1 = cvt8(qb10, qb11);
    if (kt + 1 < 32) {
      const int ko = (kt + 1) * 32;
      qa00 = *(const float4*)(Ag0 + ko); qa01 = *(const float4*)(Ag0 + ko + 4);
      qa10 = *(const float4*)(Ag1 + ko); qa11 = *(const float4*)(Ag1 + ko + 4);
      qb00 = *(const float4*)(Bg0 + ko); qb01 = *(const float4*)(Bg0 + ko + 4);
      qb10 = *(const float4*)(Bg1 + ko); qb11 = *(const float4*)(Bg1 + ko + 4);
    }
    __syncthreads();

    bf16x8 af[4], bfr[4];
#pragma unroll
    for (int mi = 0; mi < 4; ++mi)
      af[mi] = *(const bf16x8*)(As + (wm * 64 + mi * 16 + col) * 32 + quad * 8);
#pragma unroll
    for (int ni = 0; ni < 4; ++ni)
      bfr[ni] = *(const bf16x8*)(Bs + (wn * 64 + ni * 16 + col) * 32 + quad * 8);

#pragma unroll
    for (int mi = 0; mi < 4; ++mi)
#pragma unroll
      for (int ni = 0; ni < 4; ++ni)
        acc[mi][ni] = __builtin_amdgcn_mfma_f32_16x16x32_bf16(af[mi], bfr[ni], acc[mi][ni], 0, 0, 0);
  }

  // epilogue: tanh -> *w[o] -> reduce over this block's 128 o-columns.
  // C/D layout (verified m89): col = lane&15, row = quad*4 + reg.
  float wv[4];
#pragma unroll
  for (int ni = 0; ni < 4; ++ni) wv[ni] = w[n0 + wn * 64 + ni * 16 + col];

  float ppv[4][4];
#pragma unroll
  for (int mi = 0; mi < 4; ++mi) {
#pragma unroll
    for (int reg = 0; reg < 4; ++reg) {
      float pp = 0.f;
#pragma unroll
      for (int ni = 0; ni < 4; ++ni) pp += fast_tanh(acc[mi][ni][reg]) * wv[ni];
      pp += __shfl_xor(pp, 1);
      pp += __shfl_xor(pp, 2);
      pp += __shfl_xor(pp, 4);
      pp += __shfl_xor(pp, 8);
      ppv[mi][reg] = pp;   // valid where col==0
    }
  }

  if (wn == 0 && col == 0) {
#pragma unroll
    for (int mi = 0; mi < 4; ++mi)
#pragma unroll
      for (int reg = 0; reg < 4; ++reg)
        sred[wm * 64 + mi * 16 + quad * 4 + reg] = ppv[mi][reg];
  }
  __syncthreads();
  if (wn == 1 && col == 0) {
#pragma unroll
    for (int mi = 0; mi < 4; ++mi)
#pragma unroll
      for (int reg = 0; reg < 4; ++reg) {
        int ml = wm * 64 + mi * 16 + quad * 4 + reg;
        sp[(size_t)(m0 + ml) * 8 + ny] = sred[ml] + ppv[mi][reg];
      }
  }
}

// ---------------------------------------------------------------- kernel 2
// Sum 8 partials -> logits -> per-batch softmax.
__global__ __launch_bounds__(512)
void softmax_kernel(const float* __restrict__ sPartD, const float* __restrict__ sPartB,
                    float* __restrict__ q, float* __restrict__ p) {
  __shared__ float red[8];
  const int b = blockIdx.x, tid = threadIdx.x;
  const int wave = tid >> 6, lane = tid & 63;

  {  // dns side, 512 logits
    const float4* p4 = (const float4*)(sPartD + (size_t)(b * S_ + tid) * 8);
    float4 x0 = p4[0], x1 = p4[1];
    float x = x0.x + x0.y + x0.z + x0.w + x1.x + x1.y + x1.z + x1.w;
    float wm = x;
#pragma unroll
    for (int msk = 32; msk; msk >>= 1) wm = fmaxf(wm, __shfl_xor(wm, msk));
    if (!lane) red[wave] = wm;
    __syncthreads();
    float bm = red[0];
#pragma unroll
    for (int i = 1; i < 8; ++i) bm = fmaxf(bm, red[i]);
    __syncthreads();
    float e = __expf(x - bm);
    float ws = e;
#pragma unroll
    for (int msk = 32; msk; msk >>= 1) ws += __shfl_xor(ws, msk);
    if (!lane) red[wave] = ws;
    __syncthreads();
    float bs = 0.f;
#pragma unroll
    for (int i = 0; i < 8; ++i) bs += red[i];
    q[b * S_ + tid] = e / bs;
    __syncthreads();
  }
  {  // img side, 196 logits
    float x = -3.0e38f;
    if (tid < R_) {
      const float4* p4 = (const float4*)(sPartB + (size_t)(b * R_ + tid) * 8);
      float4 x0 = p4[0], x1 = p4[1];
      x = x0.x + x0.y + x0.z + x0.w + x1.x + x1.y + x1.z + x1.w;
    }
    float wm = x;
#pragma unroll
    for (int msk = 32; msk; msk >>= 1) wm = fmaxf(wm, __shfl_xor(wm, msk));
    if (!lane) red[wave] = wm;
    __syncthreads();
    float bm = red[0];
#pragma unroll
    for (int i = 1; i < 8; ++i) bm = fmaxf(bm, red[i]);
    __syncthreads();
    float e = (tid < R_) ? __expf(x - bm) : 0.f;
    float ws = e;
#pragma unroll
    for (int msk = 32; msk; msk >>= 1) ws += __shfl_xor(ws, msk);
    if (!lane) red[wave] = ws;
    __syncthreads();
    float bs = 0.f;
#pragma unroll
    for (int i = 0; i < 8; ++i) bs += red[i];
    if (tid < R_) p[b * R_ + tid] = e / bs;
  }
}

// ---------------------------------------------------------------- kernel 3
// Weighted sums, pure stores of per-j-chunk partials (no atomics), FP32 math.
//   uPart[c*BH + b*H + h] = sum_{j in chunk c} q[b,j]*dns[b,j,h]   c=0..7 (64 j)
//   vPart[c*BH + b*H + h] = sum_{r in chunk c} p[b,r]*img[b,r,h]   c=0..3 (49 r)
__global__ __launch_bounds__(256)
void wsum_kernel(const float* __restrict__ dns, const float* __restrict__ img,
                 const float* __restrict__ q, const float* __restrict__ p,
                 float* __restrict__ uPart, float* __restrict__ vPart) {
  __shared__ float qs[64];
  const int b = blockIdx.x, tid = threadIdx.x;
  const int zc = blockIdx.y;
  const float* X; const float* wq; float* outp; int J, j0, jn;
  if (zc < 8) { X = dns; wq = q; outp = uPart + zc * BH;       J = S_; j0 = zc * 64;       jn = 64; }
  else        { X = img; wq = p; outp = vPart + (zc - 8) * BH; J = R_; j0 = (zc - 8) * 49; jn = 49; }
  if (tid < jn) qs[tid] = wq[b * J + j0 + tid];
  __syncthreads();
  const int h = tid * 4;
  float4 a = {0.f, 0.f, 0.f, 0.f};
  for (int jj = 0; jj < jn; ++jj) {
    float4 xv = *(const float4*)(X + ((size_t)(b * J + j0 + jj) * H_ + h));
    float qv = qs[jj];
    a.x += qv * xv.x; a.y += qv * xv.y; a.z += qv * xv.z; a.w += qv * xv.w;
  }
  *(float4*)(outp + (size_t)b * H_ + h) = a;
}

// ---------------------------------------------------------------- kernel 3b
// Combine partials: u[b,h] = sum_{c<8} uPart[c], v[b,h] = sum_{c<4} vPart[c].
// grid (B), 256 threads, one float4 per thread per array.
__global__ __launch_bounds__(256)
void combine_kernel(const float* __restrict__ uPart, const float* __restrict__ vPart,
                    float* __restrict__ u, float* __restrict__ v) {
  const int b = blockIdx.x, tid = threadIdx.x;
  const int i = b * 256 + tid;   // float4 index into (B,H)
  float4 a = {0.f, 0.f, 0.f, 0.f};
#pragma unroll
  for (int c = 0; c < 8; ++c) {
    float4 s = ((const float4*)(uPart + (size_t)c * BH))[i];
    a.x += s.x; a.y += s.y; a.z += s.z; a.w += s.w;
  }
  ((float4*)u)[i] = a;
  float4 cacc = {0.f, 0.f, 0.f, 0.f};
#pragma unroll
  for (int c = 0; c < 4; ++c) {
    float4 s = ((const float4*)(vPart + (size_t)c * BH))[i];
    cacc.x += s.x; cacc.y += s.y; cacc.z += s.z; cacc.w += s.w;
  }
  ((float4*)v)[i] = cacc;
}

// ---------------------------------------------------------------- kernel 4
// Broadcast write, FP32 OUTPUT (the reference returns float32 tensors):
//   out0[b,s,:] = u[b,:]  (16,777,216 floats), out1[b,s,:] = v[b,:].
// PER4 = B*S*H/4 = 4,194,304 float4 stores per tensor; grid exactly covers 2*PER4.
__global__ __launch_bounds__(256)
void bcast_kernel(const float* __restrict__ u, const float* __restrict__ v,
                  float* __restrict__ out) {
  const int PER4 = B_ * S_ * H_ / 4;              // 4,194,304
  const int t = blockIdx.x * 256 + threadIdx.x;   // 0 .. 2*PER4-1
  const int which = (t >= PER4);
  const int r = t - which * PER4;
  const int b = r >> 17;        // S*H/4 = 131072 float4 per batch
  const int h4 = r & 255;       // H/4 = 256 float4 per row
  const float4 val = ((const float4*)((which ? v : u) + (size_t)b * H_))[h4];
  ((float4*)out)[t] = val;
}

// ---------------------------------------------------------------- launch

extern "C" void kernel_launch(void* const* d_in, const int* in_sizes, int n_in,
                              void* d_out, int out_size, void* d_ws, size_t ws_size,
                              hipStream_t stream) {
  const float* dns   = (const float*)d_in[0];
  const float* img   = (const float*)d_in[1];
  const float* Wi1   = (const float*)d_in[4];
  const float* watt1 = (const float*)d_in[5];
  const float* Wd2   = (const float*)d_in[7];
  const float* watt2 = (const float*)d_in[10];
  float* out = (float*)d_out;   // fp32 output (reference returns float32)

  float* ws = (float*)d_ws;
  float* sPartD = ws;              // 16384*8 = 131072
  float* sPartB = ws + 131072;     // 6272*8  =  50176
  float* q      = ws + 181248;     // 16384
  float* p      = ws + 197632;     // 6272
  float* uPart  = ws + 203904;     // 8*32768 = 262144
  float* vPart  = ws + 466048;     // 4*32768 = 131072
  float* u      = ws + 597120;     // 32768
  float* v      = ws + 629888;     // 32768   (total 662656 floats ~ 2.65 MB)

  score_gemm_kernel<<<dim3(128 + 49, 8), 256, 0, stream>>>(
      dns, img, Wd2, Wi1, watt1, watt2, sPartD, sPartB);
  softmax_kernel<<<B_, 512, 0, stream>>>(sPartD, sPartB, q, p);
  wsum_kernel<<<dim3(B_, 12), 256, 0, stream>>>(dns, img, q, p, uPart, vPart);
  combine_kernel<<<B_, 256, 0, stream>>>(uPart, vPart, u, v);
  bcast_kernel<<<32768, 256, 0, stream>>>(u, v, out);
}